// Round 3
// baseline (1150.621 us; speedup 1.0000x reference)
//
#include <hip/hip_runtime.h>
#include <stdint.h>

// IcoPool inverted: instead of 146.8M random global gathers (transaction-bound,
// ~2.7 cyc/line-request in the TA/L2 path), stream x sequentially and
// scatter-add into an LDS-resident output accumulator (LDS handles random
// scatter ~10x cheaper). Inverse edge list built on-device in d_ws each call.

constexpr int B = 8, F = 64, V_IN = 163842, V_OUT = 40962, K = 7;
constexpr int ROWS = B * F;              // 512
constexpr int NE   = V_OUT * K;          // 286734 edges
constexpr int QSZ  = 10241;              // V_OUT quarter (last = 10239); 4*QSZ >= V_OUT
constexpr int NQ   = 4;
constexpr int BPQ  = (V_IN >> 8) + 1;    // 641 i-buckets per quarter (i>>8 in [0,640])
constexpr int NBINS = NQ * BPQ;          // 2564

// ---------------- preprocessing ----------------

__global__ void zero_counts(int* __restrict__ counts) {
    int t = blockIdx.x * blockDim.x + threadIdx.x;
    if (t < NBINS) counts[t] = 0;
}

__global__ void hist_edges(const int* __restrict__ nidx, int* __restrict__ counts) {
    int e = blockIdx.x * blockDim.x + threadIdx.x;
    if (e >= NE) return;
    int v = e / K;
    int i = nidx[e];
    int q = v / QSZ;
    atomicAdd(&counts[q * BPQ + (i >> 8)], 1);
}

__global__ __launch_bounds__(1024) void scan_bins(const int* __restrict__ counts,
                                                  int* __restrict__ offsets,
                                                  int* __restrict__ cursor) {
    __shared__ int sa[NBINS], sb[NBINS];
    int* src = sa;
    int* dst = sb;
    for (int t = threadIdx.x; t < NBINS; t += 1024) sa[t] = counts[t];
    __syncthreads();
    for (int d = 1; d < NBINS; d <<= 1) {          // Hillis-Steele inclusive scan
        for (int t = threadIdx.x; t < NBINS; t += 1024)
            dst[t] = (t >= d) ? (src[t] + src[t - d]) : src[t];
        __syncthreads();
        int* tmp = src; src = dst; dst = tmp;
    }
    for (int t = threadIdx.x; t < NBINS; t += 1024) {
        int ex = (t == 0) ? 0 : src[t - 1];
        offsets[t] = ex;
        cursor[t]  = ex;
    }
    if (threadIdx.x == 0) offsets[NBINS] = src[NBINS - 1];  // == NE
}

// edge word: i (18 bits) << 14 | v_local (14 bits, < QSZ=10241 < 16384)
__global__ void fill_edges(const int* __restrict__ nidx, int* __restrict__ cursor,
                           uint32_t* __restrict__ edges) {
    int e = blockIdx.x * blockDim.x + threadIdx.x;
    if (e >= NE) return;
    int v = e / K;
    int i = nidx[e];
    int q = v / QSZ;
    int vl = v - q * QSZ;
    int pos = atomicAdd(&cursor[q * BPQ + (i >> 8)], 1);
    edges[pos] = ((uint32_t)i << 14) | (uint32_t)vl;
}

// ---------------- main pool kernel ----------------

constexpr int TPB_P = 512;

__global__ __launch_bounds__(TPB_P) void pool_scatter(
    const float* __restrict__ x, const uint32_t* __restrict__ edges,
    const int* __restrict__ offsets, float* __restrict__ out)
{
    __shared__ float acc[QSZ];   // 40.96 KB -> 3 blocks/CU (24 waves)

    const int b   = blockIdx.x;
    const int xcd = b & 7;            // HW round-robin XCD assignment
    const int j   = b >> 3;           // 0..255 per XCD
    const int row = xcd * (ROWS / 8) + (j >> 2);  // 64 rows per XCD, row slow
    const int q   = j & 3;            // 4 quarter-blocks of a row adjacent -> share L2 fetch
    const int qbase = q * QSZ;
    const int qlen  = min(QSZ, V_OUT - qbase);

    for (int t = threadIdx.x; t < qlen; t += TPB_P) acc[t] = 0.0f;
    __syncthreads();

    const int start = offsets[q * BPQ];
    const int end   = offsets[(q + 1) * BPQ];
    const float* __restrict__ xr = x + (size_t)row * V_IN;

    for (int e = start + (int)threadIdx.x; e < end; e += TPB_P) {
        uint32_t u = edges[e];              // sequential, coalesced
        int i  = (int)(u >> 14);            // ~ascending -> x reads stream in order
        int vl = (int)(u & 16383u);
        atomicAdd(&acc[vl], xr[i]);         // ds_add_f32, random bank
    }
    __syncthreads();

    float* orow = out + (size_t)row * V_OUT + qbase;
    for (int t = threadIdx.x; t < qlen; t += TPB_P)
        __builtin_nontemporal_store(acc[t] * (1.0f / 7.0f), orow + t);
}

// ---------------- fallback (round-2 gather) ----------------

constexpr int RPB = 2, TPB = 256;
constexpr int VB  = (V_OUT + TPB - 1) / TPB;
constexpr int RGS = ROWS / RPB;
constexpr int RG_PER_XCD = RGS / 8;
constexpr int FB_BLOCKS  = RGS * VB;

__global__ __launch_bounds__(TPB) void icopool_gather(
    const float* __restrict__ x, const int* __restrict__ nidx,
    float* __restrict__ out)
{
    const int b = blockIdx.x;
    const int xcd = b & 7, j = b >> 3;
    const int rg  = xcd * RG_PER_XCD + (j / VB);
    const int vb  = j % VB;
    const int r0  = rg * RPB;
    const int v = vb * TPB + threadIdx.x;
    if (v >= V_OUT) return;
    const int base = v * K;
    const int i0 = nidx[base+0], i1 = nidx[base+1], i2 = nidx[base+2],
              i3 = nidx[base+3], i4 = nidx[base+4], i5 = nidx[base+5],
              i6 = nidx[base+6];
    #pragma unroll
    for (int r = 0; r < RPB; ++r) {
        const float* xr = x + (size_t)(r0 + r) * V_IN;
        float s = xr[i0]+xr[i1]+xr[i2]+xr[i3]+xr[i4]+xr[i5]+xr[i6];
        __builtin_nontemporal_store(s * (1.0f/7.0f), out + (size_t)(r0+r) * V_OUT + v);
    }
}

// ---------------- launch ----------------

extern "C" void kernel_launch(void* const* d_in, const int* in_sizes, int n_in,
                              void* d_out, int out_size, void* d_ws, size_t ws_size,
                              hipStream_t stream) {
    const float* x    = (const float*)d_in[0];
    const int*   nidx = (const int*)d_in[1];
    float*       out  = (float*)d_out;

    // ws layout (4-byte words): counts[NBINS] | offsets[NBINS+1] | cursor[NBINS] | edges[NE]
    const size_t need = (size_t)(NBINS + (NBINS + 1) + NBINS + NE) * 4;
    if (ws_size < need) {
        icopool_gather<<<dim3(FB_BLOCKS), dim3(TPB), 0, stream>>>(x, nidx, out);
        return;
    }
    int* counts       = (int*)d_ws;
    int* offsets      = counts + NBINS;
    int* cursor       = offsets + (NBINS + 1);
    uint32_t* edges   = (uint32_t*)(cursor + NBINS);

    zero_counts<<<dim3((NBINS + 255) / 256), dim3(256), 0, stream>>>(counts);
    hist_edges <<<dim3((NE + 255) / 256),   dim3(256), 0, stream>>>(nidx, counts);
    scan_bins  <<<dim3(1), dim3(1024), 0, stream>>>(counts, offsets, cursor);
    fill_edges <<<dim3((NE + 255) / 256),   dim3(256), 0, stream>>>(nidx, cursor, edges);
    pool_scatter<<<dim3(ROWS * NQ), dim3(TPB_P), 0, stream>>>(x, edges, offsets, out);
}